// Round 10
// baseline (1040.264 us; speedup 1.0000x reference)
//
#include <hip/hip_runtime.h>

#define E_NUM 16
#define DM 2048
#define DH 1408
#define NTOK 32768
#define TMAX 144           // sum_e ceil(c_e/256) <= 128 + 16; 144 = 8*18
#define TILE_U16 8192      // one 128x64 bf16 image
#define XI_RS (32 * TILE_U16)   // u16 per 128-row X image group (32 ktiles)
#define HT_RS (22 * TILE_U16)   // u16 per 128-row H image group (22 ktiles)

typedef unsigned short u16;
typedef unsigned int u32;
typedef float f32x4 __attribute__((ext_vector_type(4)));
typedef __bf16 bf16x8 __attribute__((ext_vector_type(8)));
typedef short short8 __attribute__((ext_vector_type(8)));

__device__ __forceinline__ u16 f2bf(float x) {
  u32 u = __builtin_bit_cast(u32, x);
  u = (u + 0x7FFFu + ((u >> 16) & 1u)) >> 16;   // RNE
  return (u16)u;
}
__device__ __forceinline__ u32 f2bf2(float lo, float hi) {
  return (u32)f2bf(lo) | ((u32)f2bf(hi) << 16);
}

template <typename V>
__device__ __forceinline__ auto mfma_16x16x32(V a, V b, f32x4 c, int)
    -> decltype(__builtin_amdgcn_mfma_f32_16x16x32_bf16(a, b, c, 0, 0, 0)) {
  return __builtin_amdgcn_mfma_f32_16x16x32_bf16(a, b, c, 0, 0, 0);
}
template <typename V>
__device__ __forceinline__ f32x4 mfma_16x16x32(V a, V b, f32x4 c, long) {
  return __builtin_amdgcn_mfma_f32_16x16x32_bf16(
      __builtin_bit_cast(short8, a), __builtin_bit_cast(short8, b), c, 0, 0, 0);
}
__device__ __forceinline__ f32x4 MFMA(bf16x8 a, bf16x8 b, f32x4 c) {
  return mfma_16x16x32(a, b, c, 0);
}

__device__ __forceinline__ void gll16(const void* g, void* l) {
  __builtin_amdgcn_global_load_lds((const u32*)g, (u32*)l, 16, 0, 0);
}
__device__ __forceinline__ bf16x8 ld_frag(const u16* p) {
  return __builtin_bit_cast(bf16x8, *(const uint4*)p);
}

// ---------------------------------------------------------------------------
// X tiler: f32 [NTOK][DM] -> bf16 images [256][32][8192], phys chunk = c^(row&7)
// ---------------------------------------------------------------------------
__global__ void xtile(const float* __restrict__ src, u16* __restrict__ dst) {
  const int kt = blockIdx.x;   // 0..31
  const int rt = blockIdx.y;   // 0..255
  const int tid = threadIdx.x;
  const float* s = src + (size_t)rt * 128 * DM + kt * 64;
  u16* d = dst + (size_t)rt * XI_RS + (size_t)kt * TILE_U16;
#pragma unroll
  for (int i = 0; i < 4; ++i) {
    int u = i * 256 + tid;
    int row = u >> 3, c = u & 7;
    const float* p = s + (size_t)row * DM + c * 8;
    float4 v0 = *(const float4*)p, v1 = *(const float4*)(p + 4);
    uint4 w;
    w.x = f2bf2(v0.x, v0.y); w.y = f2bf2(v0.z, v0.w);
    w.z = f2bf2(v1.x, v1.y); w.w = f2bf2(v1.z, v1.w);
    *(uint4*)&d[(size_t)row * 64 + ((c ^ (row & 7)) * 8)] = w;
  }
}

// ---------------------------------------------------------------------------
// Weight tiler v2: f32 [E][K][N] -> bf16 images [E][N/128][K/64][8192]
// ---------------------------------------------------------------------------
__global__ void wtile(const float* __restrict__ src, u16* __restrict__ dst,
                      int K, int N) {
  __shared__ float t[64][133];
  const int kt = blockIdx.x, nt = blockIdx.y, e = blockIdx.z;
  const int tid = threadIdx.x;
  const size_t sbase = (size_t)e * K * N + (size_t)kt * 64 * N + (size_t)nt * 128;

#pragma unroll
  for (int i = 0; i < 8; i++) {
    int uid = i * 256 + tid;
    int kr = uid >> 5, nc = (uid & 31) * 4;
    float4 v = *(const float4*)&src[sbase + (size_t)kr * N + nc];
    t[kr][nc + 0] = v.x; t[kr][nc + 1] = v.y;
    t[kr][nc + 2] = v.z; t[kr][nc + 3] = v.w;
  }
  __syncthreads();
  const size_t dbase = (((size_t)e * (N / 128) + nt) * (K / 64) + kt) * TILE_U16;
#pragma unroll
  for (int i = 0; i < 4; i++) {
    int uid = i * 256 + tid;
    int row = uid >> 3, c = uid & 7;
    int kc = (c ^ (row & 7)) * 8;
    uint4 w;
    w.x = f2bf2(t[kc + 0][row], t[kc + 1][row]);
    w.y = f2bf2(t[kc + 2][row], t[kc + 3][row]);
    w.z = f2bf2(t[kc + 4][row], t[kc + 5][row]);
    w.w = f2bf2(t[kc + 6][row], t[kc + 7][row]);
    *(uint4*)&dst[dbase + uid * 8] = w;
  }
}

// Map linear 256-row tile index -> (expert, row0, valid).
__device__ __forceinline__ bool tile_map(const int* __restrict__ cnt, int t,
                                         int& e_out, int& row0, int& valid) {
  int e = -1, ti = 0, seg0 = 0, segc = 0, tacc = 0, off = 0;
#pragma unroll
  for (int i = 0; i < E_NUM; i++) {
    int ci = cnt[i];
    int nt = (ci + 255) >> 8;
    if (e < 0 && t < tacc + nt) { e = i; ti = t - tacc; seg0 = off; segc = ci; }
    tacc += nt; off += ci;
  }
  if (e < 0) return false;
  e_out = e;
  row0 = seg0 + ti * 256;
  int v = seg0 + segc - row0;
  valid = v < 256 ? v : 256;
  return true;
}

__device__ __forceinline__ int xcd_swz(int bx) {
  return (bx & 7) * (TMAX / 8) + (bx >> 3);
}

// ---------------------------------------------------------------------------
// Fused gate+up grouped GEMM + SwiGLU. BM=256, BN=128, 512 thr, 8 waves
// (4 row x 2 col), 64 KiB single-buffered LDS, pure-gll staging,
// 2 barriers/K-tile, 2 blocks/CU. MFMA = 16x16x32 (proven conflict-free).
// ---------------------------------------------------------------------------
__global__ __launch_bounds__(512, 2) void gemm_gate_up(
    const u16* __restrict__ Xi, const u16* __restrict__ WgT,
    const u16* __restrict__ WuT, const int* __restrict__ cnt,
    u16* __restrict__ H) {
  __shared__ u16 As[2 * TILE_U16];   // 32 KiB (256 rows)
  __shared__ u16 Bg[TILE_U16];       // 16 KiB
  __shared__ u16 Bu[TILE_U16];       // 16 KiB

  int e, row0, valid;
  if (!tile_map(cnt, xcd_swz(blockIdx.x), e, row0, valid)) return;
  const int n0t = blockIdx.y;  // 0..10

  const int tid = threadIdx.x;
  const int lane = tid & 63;
  const int wave = tid >> 6;                 // 0..7
  const int wr = (wave >> 1) * 64;           // 0,64,128,192
  const int wcn = (wave & 1) * 64;           // 0,64
  const int l15 = lane & 15, l4 = lane >> 4;
  const int swz = l15 & 7;

  // staging sources: unit u = q*512+tid -> lds row lr=u>>3, phys chunk cs=u&7
  const u16* pA[4];
#pragma unroll
  for (int q = 0; q < 4; ++q) {
    int u = q * 512 + tid;
    int lr = u >> 3, cs = u & 7;
    int R = row0 + (lr < valid ? lr : 0);
    int srcc = cs ^ (lr & 7) ^ (R & 7);
    pA[q] = Xi + (size_t)(R >> 7) * XI_RS + (size_t)(R & 127) * 64 + srcc * 8;
  }
  const size_t btb = (((size_t)e * 11 + n0t) * 32) * TILE_U16;
  const u16* pBg[2];
  const u16* pBu[2];
#pragma unroll
  for (int q = 0; q < 2; ++q) {
    pBg[q] = WgT + btb + (q * 512 + tid) * 8;
    pBu[q] = WuT + btb + (q * 512 + tid) * 8;
  }

  // per-lane frag read pointers (static, single buffer)
  const int arow = (wr + l15) * 64;
  const int brow = (wcn + l15) * 64;
  const int c0 = (l4 ^ swz) * 8;
  const int c1 = ((4 + l4) ^ swz) * 8;
  const u16* pa0 = &As[arow + c0];
  const u16* pa1 = &As[arow + c1];
  const u16* pg0 = &Bg[brow + c0];
  const u16* pg1 = &Bg[brow + c1];
  const u16* pu0 = &Bu[brow + c0];
  const u16* pu1 = &Bu[brow + c1];

  f32x4 accg[4][4], accu[4][4];
#pragma unroll
  for (int i = 0; i < 4; i++)
#pragma unroll
    for (int j = 0; j < 4; j++) {
      accg[i][j] = (f32x4){0.f, 0.f, 0.f, 0.f};
      accu[i][j] = (f32x4){0.f, 0.f, 0.f, 0.f};
    }

  for (int kt = 0; kt < 32; ++kt) {
    const size_t ko = (size_t)kt * TILE_U16;
#pragma unroll
    for (int q = 0; q < 4; ++q) gll16(pA[q] + ko, &As[(q * 512 + tid) * 8]);
#pragma unroll
    for (int q = 0; q < 2; ++q) {
      const int u8 = (q * 512 + tid) * 8;
      gll16(pBg[q] + ko, &Bg[u8]);
      gll16(pBu[q] + ko, &Bu[u8]);
    }
    __syncthreads();   // drains glls; tile visible
#pragma unroll
    for (int kh = 0; kh < 2; ++kh) {
      bf16x8 af[4], bgv[4], buv[4];
#pragma unroll
      for (int i = 0; i < 4; ++i)
        af[i] = ld_frag((kh ? pa1 : pa0) + i * 1024);
#pragma unroll
      for (int j = 0; j < 4; ++j) {
        bgv[j] = ld_frag((kh ? pg1 : pg0) + j * 1024);
        buv[j] = ld_frag((kh ? pu1 : pu0) + j * 1024);
      }
#pragma unroll
      for (int j = 0; j < 4; ++j)
#pragma unroll
        for (int i = 0; i < 4; ++i) {
          accg[i][j] = MFMA(af[i], bgv[j], accg[i][j]);
          accu[i][j] = MFMA(af[i], buv[j], accu[i][j]);
        }
    }
    __syncthreads();   // readers done before next stage overwrites
  }

  // epilogue: h = silu(gate)*up -> H swizzled images
#pragma unroll
  for (int j = 0; j < 4; ++j) {
    int col = n0t * 128 + wcn + j * 16 + l15;
    int kt_h = col >> 6, cc = (col & 63) >> 3, ce = col & 7;
#pragma unroll
    for (int i = 0; i < 4; ++i) {
      f32x4 g = accg[i][j], u = accu[i][j];
#pragma unroll
      for (int r = 0; r < 4; ++r) {
        int rl = wr + i * 16 + l4 * 4 + r;
        if (rl < valid) {
          int R = row0 + rl;
          float gv = g[r];
          float hv = gv / (1.f + __expf(-gv)) * u[r];
          size_t idx = (size_t)(R >> 7) * HT_RS + (size_t)kt_h * TILE_U16 +
                       (size_t)(R & 127) * 64 + ((cc ^ (R & 7)) * 8) + ce;
          H[idx] = f2bf(hv);
        }
      }
    }
  }
}

// ---------------------------------------------------------------------------
// Down grouped GEMM. BM=256, BN=128, 512 thr, 48 KiB LDS, 3 blocks/CU.
// ---------------------------------------------------------------------------
__global__ __launch_bounds__(512, 3) void gemm_down(
    const u16* __restrict__ Ht, const u16* __restrict__ WdT,
    const int* __restrict__ cnt, float* __restrict__ Out) {
  __shared__ u16 As[2 * TILE_U16];   // 32 KiB
  __shared__ u16 Bs[TILE_U16];       // 16 KiB

  int e, row0, valid;
  if (!tile_map(cnt, xcd_swz(blockIdx.x), e, row0, valid)) return;
  const int n0t = blockIdx.y;  // 0..15

  const int tid = threadIdx.x;
  const int lane = tid & 63;
  const int wave = tid >> 6;
  const int wr = (wave >> 1) * 64, wcn = (wave & 1) * 64;
  const int l15 = lane & 15, l4 = lane >> 4;
  const int swz = l15 & 7;

  const u16* pA[4];
#pragma unroll
  for (int q = 0; q < 4; ++q) {
    int u = q * 512 + tid;
    int lr = u >> 3, cs = u & 7;
    int R = row0 + (lr < valid ? lr : 0);
    int srcc = cs ^ (lr & 7) ^ (R & 7);
    pA[q] = Ht + (size_t)(R >> 7) * HT_RS + (size_t)(R & 127) * 64 + srcc * 8;
  }
  const size_t btb = (((size_t)e * 16 + n0t) * 22) * TILE_U16;
  const u16* pB[2];
#pragma unroll
  for (int q = 0; q < 2; ++q) pB[q] = WdT + btb + (q * 512 + tid) * 8;

  const int arow = (wr + l15) * 64;
  const int brow = (wcn + l15) * 64;
  const int c0 = (l4 ^ swz) * 8;
  const int c1 = ((4 + l4) ^ swz) * 8;
  const u16* pa0 = &As[arow + c0];
  const u16* pa1 = &As[arow + c1];
  const u16* pb0 = &Bs[brow + c0];
  const u16* pb1 = &Bs[brow + c1];

  f32x4 acc[4][4];
#pragma unroll
  for (int i = 0; i < 4; i++)
#pragma unroll
    for (int j = 0; j < 4; j++) acc[i][j] = (f32x4){0.f, 0.f, 0.f, 0.f};

  for (int kt = 0; kt < 22; ++kt) {
    const size_t ko = (size_t)kt * TILE_U16;
#pragma unroll
    for (int q = 0; q < 4; ++q) gll16(pA[q] + ko, &As[(q * 512 + tid) * 8]);
#pragma unroll
    for (int q = 0; q < 2; ++q) gll16(pB[q] + ko, &Bs[(q * 512 + tid) * 8]);
    __syncthreads();
#pragma unroll
    for (int kh = 0; kh < 2; ++kh) {
      bf16x8 af[4], bv[4];
#pragma unroll
      for (int i = 0; i < 4; ++i)
        af[i] = ld_frag((kh ? pa1 : pa0) + i * 1024);
#pragma unroll
      for (int j = 0; j < 4; ++j)
        bv[j] = ld_frag((kh ? pb1 : pb0) + j * 1024);
#pragma unroll
      for (int j = 0; j < 4; ++j)
#pragma unroll
        for (int i = 0; i < 4; ++i) acc[i][j] = MFMA(af[i], bv[j], acc[i][j]);
    }
    __syncthreads();
  }

#pragma unroll
  for (int j = 0; j < 4; ++j) {
#pragma unroll
    for (int i = 0; i < 4; ++i) {
#pragma unroll
      for (int r = 0; r < 4; ++r) {
        int rl = wr + i * 16 + l4 * 4 + r;
        if (rl < valid)
          Out[(size_t)(row0 + rl) * DM + n0t * 128 + wcn + j * 16 + l15] =
              acc[i][j][r];
      }
    }
  }
}

extern "C" void kernel_launch(void* const* d_in, const int* in_sizes, int n_in,
                              void* d_out, int out_size, void* d_ws, size_t ws_size,
                              hipStream_t stream) {
  const float* inp = (const float*)d_in[0];
  const float* w_gate = (const float*)d_in[1];
  const float* w_up = (const float*)d_in[2];
  const float* w_down = (const float*)d_in[3];
  const int* cnt = (const int*)d_in[4];
  float* out = (float*)d_out;

  const size_t XI_ELEMS = (size_t)NTOK * DM;       // 128 MiB as bf16
  const size_t WELEMS = (size_t)E_NUM * DM * DH;   // 88 MiB as bf16
  if (ws_size < (XI_ELEMS + 3 * WELEMS) * sizeof(u16)) return;

  u16* Xi = (u16*)d_ws;        // X images [256][32][8192]
  u16* wgT = Xi + XI_ELEMS;    // gate tiles [E][11][32][8192]; later w_down
  u16* wuT = wgT + WELEMS;     // up tiles
  u16* Ht = wuT + WELEMS;      // H images [256][22][8192]

  xtile<<<dim3(32, 256), 256, 0, stream>>>(inp, Xi);
  wtile<<<dim3(DM / 64, DH / 128, E_NUM), 256, 0, stream>>>(w_gate, wgT, DM, DH);
  wtile<<<dim3(DM / 64, DH / 128, E_NUM), 256, 0, stream>>>(w_up, wuT, DM, DH);
  gemm_gate_up<<<dim3(TMAX, DH / 128), 512, 0, stream>>>(Xi, wgT, wuT, cnt, Ht);
  // wgT region dead now; reuse for w_down tiles [E][16][22][8192]
  wtile<<<dim3(DH / 64, DM / 128, E_NUM), 256, 0, stream>>>(w_down, wgT, DH, DM);
  gemm_down<<<dim3(TMAX, DM / 128), 512, 0, stream>>>(Ht, wgT, cnt, out);
}

// Round 11
// 920.299 us; speedup vs baseline: 1.1304x; 1.1304x over previous
//
#include <hip/hip_runtime.h>

#define E_NUM 16
#define DM 2048
#define DH 1408
#define NTOK 32768
#define TMAX 272           // sum_e ceil(c_e/128) <= 256 + 16; 272 = 8*34
#define TILE_U16 8192      // one 128x64 bf16 image
#define XI_RS (32 * TILE_U16)   // u16 per 128-row X image group (32 ktiles)
#define HT_RS (22 * TILE_U16)   // u16 per 128-row H image group (22 ktiles)

typedef unsigned short u16;
typedef unsigned int u32;
typedef float f32x4 __attribute__((ext_vector_type(4)));
typedef __bf16 bf16x8 __attribute__((ext_vector_type(8)));
typedef short short8 __attribute__((ext_vector_type(8)));

__device__ __forceinline__ u16 f2bf(float x) {
  u32 u = __builtin_bit_cast(u32, x);
  u = (u + 0x7FFFu + ((u >> 16) & 1u)) >> 16;   // RNE
  return (u16)u;
}
__device__ __forceinline__ u32 f2bf2(float lo, float hi) {
  return (u32)f2bf(lo) | ((u32)f2bf(hi) << 16);
}

template <typename V>
__device__ __forceinline__ auto mfma_16x16x32(V a, V b, f32x4 c, int)
    -> decltype(__builtin_amdgcn_mfma_f32_16x16x32_bf16(a, b, c, 0, 0, 0)) {
  return __builtin_amdgcn_mfma_f32_16x16x32_bf16(a, b, c, 0, 0, 0);
}
template <typename V>
__device__ __forceinline__ f32x4 mfma_16x16x32(V a, V b, f32x4 c, long) {
  return __builtin_amdgcn_mfma_f32_16x16x32_bf16(
      __builtin_bit_cast(short8, a), __builtin_bit_cast(short8, b), c, 0, 0, 0);
}
__device__ __forceinline__ f32x4 MFMA(bf16x8 a, bf16x8 b, f32x4 c) {
  return mfma_16x16x32(a, b, c, 0);
}

__device__ __forceinline__ void gll16(const void* g, void* l) {
  __builtin_amdgcn_global_load_lds((const u32*)g, (u32*)l, 16, 0, 0);
}
__device__ __forceinline__ bf16x8 ld_frag(const u16* p) {
  return __builtin_bit_cast(bf16x8, *(const uint4*)p);
}

// ---------------------------------------------------------------------------
// X tiler: f32 [NTOK][DM] -> bf16 images [256][32][8192], phys chunk = c^(row&7)
// ---------------------------------------------------------------------------
__global__ void xtile(const float* __restrict__ src, u16* __restrict__ dst) {
  const int kt = blockIdx.x;   // 0..31
  const int rt = blockIdx.y;   // 0..255
  const int tid = threadIdx.x;
  const float* s = src + (size_t)rt * 128 * DM + kt * 64;
  u16* d = dst + (size_t)rt * XI_RS + (size_t)kt * TILE_U16;
#pragma unroll
  for (int i = 0; i < 4; ++i) {
    int u = i * 256 + tid;
    int row = u >> 3, c = u & 7;
    const float* p = s + (size_t)row * DM + c * 8;
    float4 v0 = *(const float4*)p, v1 = *(const float4*)(p + 4);
    uint4 w;
    w.x = f2bf2(v0.x, v0.y); w.y = f2bf2(v0.z, v0.w);
    w.z = f2bf2(v1.x, v1.y); w.w = f2bf2(v1.z, v1.w);
    *(uint4*)&d[(size_t)row * 64 + ((c ^ (row & 7)) * 8)] = w;
  }
}

// ---------------------------------------------------------------------------
// Weight tiler v2: f32 [E][K][N] -> bf16 images [E][N/128][K/64][8192]
// ---------------------------------------------------------------------------
__global__ void wtile(const float* __restrict__ src, u16* __restrict__ dst,
                      int K, int N) {
  __shared__ float t[64][133];
  const int kt = blockIdx.x, nt = blockIdx.y, e = blockIdx.z;
  const int tid = threadIdx.x;
  const size_t sbase = (size_t)e * K * N + (size_t)kt * 64 * N + (size_t)nt * 128;

#pragma unroll
  for (int i = 0; i < 8; i++) {
    int uid = i * 256 + tid;
    int kr = uid >> 5, nc = (uid & 31) * 4;
    float4 v = *(const float4*)&src[sbase + (size_t)kr * N + nc];
    t[kr][nc + 0] = v.x; t[kr][nc + 1] = v.y;
    t[kr][nc + 2] = v.z; t[kr][nc + 3] = v.w;
  }
  __syncthreads();
  const size_t dbase = (((size_t)e * (N / 128) + nt) * (K / 64) + kt) * TILE_U16;
#pragma unroll
  for (int i = 0; i < 4; i++) {
    int uid = i * 256 + tid;
    int row = uid >> 3, c = uid & 7;
    int kc = (c ^ (row & 7)) * 8;
    uint4 w;
    w.x = f2bf2(t[kc + 0][row], t[kc + 1][row]);
    w.y = f2bf2(t[kc + 2][row], t[kc + 3][row]);
    w.z = f2bf2(t[kc + 4][row], t[kc + 5][row]);
    w.w = f2bf2(t[kc + 6][row], t[kc + 7][row]);
    *(uint4*)&dst[dbase + uid * 8] = w;
  }
}

// Map linear 128-row tile index -> (expert, row0, valid).
__device__ __forceinline__ bool tile_map(const int* __restrict__ cnt, int t,
                                         int& e_out, int& row0, int& valid) {
  int e = -1, ti = 0, seg0 = 0, segc = 0, tacc = 0, off = 0;
#pragma unroll
  for (int i = 0; i < E_NUM; i++) {
    int ci = cnt[i];
    int nt = (ci + 127) >> 7;
    if (e < 0 && t < tacc + nt) { e = i; ti = t - tacc; seg0 = off; segc = ci; }
    tacc += nt; off += ci;
  }
  if (e < 0) return false;
  e_out = e;
  row0 = seg0 + ti * 128;
  int v = seg0 + segc - row0;
  valid = v < 128 ? v : 128;
  return true;
}

__device__ __forceinline__ int xcd_swz(int bx) {
  return (bx & 7) * (TMAX / 8) + (bx >> 3);
}

// ---------------------------------------------------------------------------
// Fused gate+up grouped GEMM + SwiGLU — R8 exactly: 128x128 tile, 256 thr,
// 4 waves, 48 KiB single-buffered LDS, pure-gll, 2 barriers/K-tile, 3 blk/CU.
// ---------------------------------------------------------------------------
__global__ __launch_bounds__(256, 3) void gemm_gate_up(
    const u16* __restrict__ Xi, const u16* __restrict__ WgT,
    const u16* __restrict__ WuT, const int* __restrict__ cnt,
    u16* __restrict__ H) {
  __shared__ u16 As[TILE_U16];   // 16 KiB
  __shared__ u16 Bg[TILE_U16];   // 16 KiB
  __shared__ u16 Bu[TILE_U16];   // 16 KiB

  int e, row0, valid;
  if (!tile_map(cnt, xcd_swz(blockIdx.x), e, row0, valid)) return;
  const int n0t = blockIdx.y;  // 0..10

  const int tid = threadIdx.x;
  const int lane = tid & 63;
  const int wave = tid >> 6;                 // 0..3
  const int wr = (wave >> 1) * 64, wcn = (wave & 1) * 64;
  const int l15 = lane & 15, l4 = lane >> 4;
  const int swz = l15 & 7;

  const u16* pA[4];
#pragma unroll
  for (int q = 0; q < 4; ++q) {
    int u = q * 256 + tid;
    int lr = u >> 3, cs = u & 7;
    int R = row0 + (lr < valid ? lr : 0);
    int srcc = cs ^ (lr & 7) ^ (R & 7);
    pA[q] = Xi + (size_t)(R >> 7) * XI_RS + (size_t)(R & 127) * 64 + srcc * 8;
  }
  const size_t btb = (((size_t)e * 11 + n0t) * 32) * TILE_U16;
  const u16* pBg[4];
  const u16* pBu[4];
#pragma unroll
  for (int q = 0; q < 4; ++q) {
    pBg[q] = WgT + btb + (q * 256 + tid) * 8;
    pBu[q] = WuT + btb + (q * 256 + tid) * 8;
  }

  const int arow = (wr + l15) * 64;
  const int brow = (wcn + l15) * 64;
  const int c0 = (l4 ^ swz) * 8;
  const int c1 = ((4 + l4) ^ swz) * 8;
  const u16* pa0 = &As[arow + c0];
  const u16* pa1 = &As[arow + c1];
  const u16* pg0 = &Bg[brow + c0];
  const u16* pg1 = &Bg[brow + c1];
  const u16* pu0 = &Bu[brow + c0];
  const u16* pu1 = &Bu[brow + c1];

  f32x4 accg[4][4], accu[4][4];
#pragma unroll
  for (int i = 0; i < 4; i++)
#pragma unroll
    for (int j = 0; j < 4; j++) {
      accg[i][j] = (f32x4){0.f, 0.f, 0.f, 0.f};
      accu[i][j] = (f32x4){0.f, 0.f, 0.f, 0.f};
    }

  for (int kt = 0; kt < 32; ++kt) {
    const size_t ko = (size_t)kt * TILE_U16;
#pragma unroll
    for (int q = 0; q < 4; ++q) {
      const int u8 = (q * 256 + tid) * 8;
      gll16(pA[q] + ko, &As[u8]);
      gll16(pBg[q] + ko, &Bg[u8]);
      gll16(pBu[q] + ko, &Bu[u8]);
    }
    __syncthreads();
#pragma unroll
    for (int kh = 0; kh < 2; ++kh) {
      bf16x8 af[4], bgv[4], buv[4];
#pragma unroll
      for (int i = 0; i < 4; ++i)
        af[i] = ld_frag((kh ? pa1 : pa0) + i * 1024);
#pragma unroll
      for (int j = 0; j < 4; ++j) {
        bgv[j] = ld_frag((kh ? pg1 : pg0) + j * 1024);
        buv[j] = ld_frag((kh ? pu1 : pu0) + j * 1024);
      }
#pragma unroll
      for (int j = 0; j < 4; ++j)
#pragma unroll
        for (int i = 0; i < 4; ++i) {
          accg[i][j] = MFMA(af[i], bgv[j], accg[i][j]);
          accu[i][j] = MFMA(af[i], buv[j], accu[i][j]);
        }
    }
    __syncthreads();
  }

#pragma unroll
  for (int j = 0; j < 4; ++j) {
    int col = n0t * 128 + wcn + j * 16 + l15;
    int kt_h = col >> 6, cc = (col & 63) >> 3, ce = col & 7;
#pragma unroll
    for (int i = 0; i < 4; ++i) {
      f32x4 g = accg[i][j], u = accu[i][j];
#pragma unroll
      for (int r = 0; r < 4; ++r) {
        int rl = wr + i * 16 + l4 * 4 + r;
        if (rl < valid) {
          int R = row0 + rl;
          float gv = g[r];
          float hv = gv / (1.f + __expf(-gv)) * u[r];
          size_t idx = (size_t)(R >> 7) * HT_RS + (size_t)kt_h * TILE_U16 +
                       (size_t)(R & 127) * 64 + ((cc ^ (R & 7)) * 8) + ce;
          H[idx] = f2bf(hv);
        }
      }
    }
  }
}

// ---------------------------------------------------------------------------
// Down grouped GEMM. 128x256 tile, 256 thr, 4 waves each 64x128 (4x8 frags):
// LDS-read/MFMA ratio 0.375 (was 0.75 at 64x64). LDS 48 KiB, 3 blocks/CU.
// ---------------------------------------------------------------------------
__global__ __launch_bounds__(256, 3) void gemm_down(
    const u16* __restrict__ Ht, const u16* __restrict__ WdT,
    const int* __restrict__ cnt, float* __restrict__ Out) {
  __shared__ u16 As[TILE_U16];       // 16 KiB (128 rows x 64)
  __shared__ u16 Bs[2 * TILE_U16];   // 32 KiB (256 cols as 2 images)

  int e, row0, valid;
  if (!tile_map(cnt, xcd_swz(blockIdx.x), e, row0, valid)) return;
  const int n0t = blockIdx.y;  // 0..7 (256-col groups)

  const int tid = threadIdx.x;
  const int lane = tid & 63;
  const int wave = tid >> 6;                  // 0..3
  const int wr = (wave >> 1) * 64;            // 0,64
  const int wcn = (wave & 1) * 128;           // 0,128
  const int l15 = lane & 15, l4 = lane >> 4;
  const int swz = l15 & 7;

  const u16* pA[4];
#pragma unroll
  for (int q = 0; q < 4; ++q) {
    int u = q * 256 + tid;
    int lr = u >> 3, cs = u & 7;
    int R = row0 + (lr < valid ? lr : 0);
    int srcc = cs ^ (lr & 7) ^ (R & 7);
    pA[q] = Ht + (size_t)(R >> 7) * HT_RS + (size_t)(R & 127) * 64 + srcc * 8;
  }
  // B: two consecutive n-tile images per K-tile
  const size_t btb0 = (((size_t)e * 16 + n0t * 2) * 22) * TILE_U16;
  const size_t btb1 = (((size_t)e * 16 + n0t * 2 + 1) * 22) * TILE_U16;
  const u16* pB[8];
#pragma unroll
  for (int q = 0; q < 4; ++q) {
    pB[q] = WdT + btb0 + (q * 256 + tid) * 8;
    pB[q + 4] = WdT + btb1 + (q * 256 + tid) * 8;
  }

  const int arow = (wr + l15) * 64;
  const int c0 = (l4 ^ swz) * 8;
  const int c1 = ((4 + l4) ^ swz) * 8;
  const u16* pa0 = &As[arow + c0];
  const u16* pa1 = &As[arow + c1];
  // B read base: image (wcn>>7), row l15 within image
  const u16* pb0 = &Bs[(wcn >> 7) * TILE_U16 + l15 * 64 + c0];
  const u16* pb1 = &Bs[(wcn >> 7) * TILE_U16 + l15 * 64 + c1];

  f32x4 acc[4][8];
#pragma unroll
  for (int i = 0; i < 4; i++)
#pragma unroll
    for (int j = 0; j < 8; j++) acc[i][j] = (f32x4){0.f, 0.f, 0.f, 0.f};

  for (int kt = 0; kt < 22; ++kt) {
    const size_t ko = (size_t)kt * TILE_U16;
#pragma unroll
    for (int q = 0; q < 4; ++q) gll16(pA[q] + ko, &As[(q * 256 + tid) * 8]);
#pragma unroll
    for (int q = 0; q < 8; ++q) gll16(pB[q] + ko, &Bs[(q * 256 + tid) * 8]);
    __syncthreads();
#pragma unroll
    for (int kh = 0; kh < 2; ++kh) {
      bf16x8 af[4];
#pragma unroll
      for (int i = 0; i < 4; ++i)
        af[i] = ld_frag((kh ? pa1 : pa0) + i * 1024);
#pragma unroll
      for (int j = 0; j < 8; ++j) {
        bf16x8 bv = ld_frag((kh ? pb1 : pb0) + j * 1024);
#pragma unroll
        for (int i = 0; i < 4; ++i) acc[i][j] = MFMA(af[i], bv, acc[i][j]);
      }
    }
    __syncthreads();
  }

#pragma unroll
  for (int j = 0; j < 8; ++j) {
    const int colb = n0t * 256 + wcn + j * 16 + l15;
#pragma unroll
    for (int i = 0; i < 4; ++i) {
#pragma unroll
      for (int r = 0; r < 4; ++r) {
        int rl = wr + i * 16 + l4 * 4 + r;
        if (rl < valid)
          Out[(size_t)(row0 + rl) * DM + colb] = acc[i][j][r];
      }
    }
  }
}

extern "C" void kernel_launch(void* const* d_in, const int* in_sizes, int n_in,
                              void* d_out, int out_size, void* d_ws, size_t ws_size,
                              hipStream_t stream) {
  const float* inp = (const float*)d_in[0];
  const float* w_gate = (const float*)d_in[1];
  const float* w_up = (const float*)d_in[2];
  const float* w_down = (const float*)d_in[3];
  const int* cnt = (const int*)d_in[4];
  float* out = (float*)d_out;

  const size_t XI_ELEMS = (size_t)NTOK * DM;       // 128 MiB as bf16
  const size_t WELEMS = (size_t)E_NUM * DM * DH;   // 88 MiB as bf16
  if (ws_size < (XI_ELEMS + 3 * WELEMS) * sizeof(u16)) return;

  u16* Xi = (u16*)d_ws;        // X images [256][32][8192]
  u16* wgT = Xi + XI_ELEMS;    // gate tiles [E][11][32][8192]; later w_down
  u16* wuT = wgT + WELEMS;     // up tiles
  u16* Ht = wuT + WELEMS;      // H images [256][22][8192]

  xtile<<<dim3(32, 256), 256, 0, stream>>>(inp, Xi);
  wtile<<<dim3(DM / 64, DH / 128, E_NUM), 256, 0, stream>>>(w_gate, wgT, DM, DH);
  wtile<<<dim3(DM / 64, DH / 128, E_NUM), 256, 0, stream>>>(w_up, wuT, DM, DH);
  gemm_gate_up<<<dim3(TMAX, DH / 128), 256, 0, stream>>>(Xi, wgT, wuT, cnt, Ht);
  // wgT region dead now; reuse for w_down tiles [E][16][22][8192]
  wtile<<<dim3(DH / 64, DM / 128, E_NUM), 256, 0, stream>>>(w_down, wgT, DH, DM);
  gemm_down<<<dim3(TMAX, DM / 256), 256, 0, stream>>>(Ht, wgT, cnt, out);
}

// Round 12
// 864.774 us; speedup vs baseline: 1.2029x; 1.0642x over previous
//
#include <hip/hip_runtime.h>

#define E_NUM 16
#define DM 2048
#define DH 1408
#define NTOK 32768
#define TMAX 272           // sum_e ceil(c_e/128) <= 256 + 16
#define NT_GU 11           // gate_up n0t groups (DH/128)
#define NT_DN 8            // down n0t groups (DM/256)
#define GU_BLKS (TMAX * NT_GU)   // 2992 = 8*374
#define DN_BLKS (TMAX * NT_DN)   // 2176 = 8*272
#define TILE_U16 8192      // one 128x64 bf16 image
#define XI_RS (32 * TILE_U16)   // u16 per 128-row X image group (32 ktiles)
#define HT_RS (22 * TILE_U16)   // u16 per 128-row H image group (22 ktiles)

typedef unsigned short u16;
typedef unsigned int u32;
typedef float f32x4 __attribute__((ext_vector_type(4)));
typedef __bf16 bf16x8 __attribute__((ext_vector_type(8)));
typedef short short8 __attribute__((ext_vector_type(8)));

__device__ __forceinline__ u16 f2bf(float x) {
  u32 u = __builtin_bit_cast(u32, x);
  u = (u + 0x7FFFu + ((u >> 16) & 1u)) >> 16;   // RNE
  return (u16)u;
}
__device__ __forceinline__ u32 f2bf2(float lo, float hi) {
  return (u32)f2bf(lo) | ((u32)f2bf(hi) << 16);
}

template <typename V>
__device__ __forceinline__ auto mfma_16x16x32(V a, V b, f32x4 c, int)
    -> decltype(__builtin_amdgcn_mfma_f32_16x16x32_bf16(a, b, c, 0, 0, 0)) {
  return __builtin_amdgcn_mfma_f32_16x16x32_bf16(a, b, c, 0, 0, 0);
}
template <typename V>
__device__ __forceinline__ f32x4 mfma_16x16x32(V a, V b, f32x4 c, long) {
  return __builtin_amdgcn_mfma_f32_16x16x32_bf16(
      __builtin_bit_cast(short8, a), __builtin_bit_cast(short8, b), c, 0, 0, 0);
}
__device__ __forceinline__ f32x4 MFMA(bf16x8 a, bf16x8 b, f32x4 c) {
  return mfma_16x16x32(a, b, c, 0);
}

__device__ __forceinline__ void gll16(const void* g, void* l) {
  __builtin_amdgcn_global_load_lds((const u32*)g, (u32*)l, 16, 0, 0);
}
__device__ __forceinline__ bf16x8 ld_frag(const u16* p) {
  return __builtin_bit_cast(bf16x8, *(const uint4*)p);
}

// ---------------------------------------------------------------------------
// X tiler: f32 [NTOK][DM] -> bf16 images [256][32][8192], phys chunk = c^(row&7)
// ---------------------------------------------------------------------------
__global__ void xtile(const float* __restrict__ src, u16* __restrict__ dst) {
  const int kt = blockIdx.x;   // 0..31
  const int rt = blockIdx.y;   // 0..255
  const int tid = threadIdx.x;
  const float* s = src + (size_t)rt * 128 * DM + kt * 64;
  u16* d = dst + (size_t)rt * XI_RS + (size_t)kt * TILE_U16;
#pragma unroll
  for (int i = 0; i < 4; ++i) {
    int u = i * 256 + tid;
    int row = u >> 3, c = u & 7;
    const float* p = s + (size_t)row * DM + c * 8;
    float4 v0 = *(const float4*)p, v1 = *(const float4*)(p + 4);
    uint4 w;
    w.x = f2bf2(v0.x, v0.y); w.y = f2bf2(v0.z, v0.w);
    w.z = f2bf2(v1.x, v1.y); w.w = f2bf2(v1.z, v1.w);
    *(uint4*)&d[(size_t)row * 64 + ((c ^ (row & 7)) * 8)] = w;
  }
}

// ---------------------------------------------------------------------------
// Weight tiler v2: f32 [E][K][N] -> bf16 images [E][N/128][K/64][8192]
// ---------------------------------------------------------------------------
__global__ void wtile(const float* __restrict__ src, u16* __restrict__ dst,
                      int K, int N) {
  __shared__ float t[64][133];
  const int kt = blockIdx.x, nt = blockIdx.y, e = blockIdx.z;
  const int tid = threadIdx.x;
  const size_t sbase = (size_t)e * K * N + (size_t)kt * 64 * N + (size_t)nt * 128;

#pragma unroll
  for (int i = 0; i < 8; i++) {
    int uid = i * 256 + tid;
    int kr = uid >> 5, nc = (uid & 31) * 4;
    float4 v = *(const float4*)&src[sbase + (size_t)kr * N + nc];
    t[kr][nc + 0] = v.x; t[kr][nc + 1] = v.y;
    t[kr][nc + 2] = v.z; t[kr][nc + 3] = v.w;
  }
  __syncthreads();
  const size_t dbase = (((size_t)e * (N / 128) + nt) * (K / 64) + kt) * TILE_U16;
#pragma unroll
  for (int i = 0; i < 4; i++) {
    int uid = i * 256 + tid;
    int row = uid >> 3, c = uid & 7;
    int kc = (c ^ (row & 7)) * 8;
    uint4 w;
    w.x = f2bf2(t[kc + 0][row], t[kc + 1][row]);
    w.y = f2bf2(t[kc + 2][row], t[kc + 3][row]);
    w.z = f2bf2(t[kc + 4][row], t[kc + 5][row]);
    w.w = f2bf2(t[kc + 6][row], t[kc + 7][row]);
    *(uint4*)&dst[dbase + uid * 8] = w;
  }
}

// Map linear 128-row tile index -> (expert, row0, valid).
__device__ __forceinline__ bool tile_map(const int* __restrict__ cnt, int t,
                                         int& e_out, int& row0, int& valid) {
  int e = -1, ti = 0, seg0 = 0, segc = 0, tacc = 0, off = 0;
#pragma unroll
  for (int i = 0; i < E_NUM; i++) {
    int ci = cnt[i];
    int nt = (ci + 127) >> 7;
    if (e < 0 && t < tacc + nt) { e = i; ti = t - tacc; seg0 = off; segc = ci; }
    tacc += nt; off += ci;
  }
  if (e < 0) return false;
  e_out = e;
  row0 = seg0 + ti * 128;
  int v = seg0 + segc - row0;
  valid = v < 128 ? v : 128;
  return true;
}

// XCD-chunked bijective swizzle over the WHOLE linear grid (nblk % 8 == 0):
// dispatch d -> logical (d&7)*(nblk/8) + (d>>3). Within an XCD the logical ids
// are contiguous, so n0t (fastest logical axis) cycles through one A-panel's
// consumers back-to-back on the same L2.
__device__ __forceinline__ int xcd_lin(int d, int nblk) {
  return (d & 7) * (nblk >> 3) + (d >> 3);
}

// ---------------------------------------------------------------------------
// Fused gate+up grouped GEMM + SwiGLU — R8 structure: 128x128 tile, 256 thr,
// 4 waves, 48 KiB single-buffered LDS, pure-gll, 2 barriers/K-tile, 3 blk/CU.
// Grid: linear 2992 blocks; n0t fastest within XCD chunk (A-panel L2 reuse).
// ---------------------------------------------------------------------------
__global__ __launch_bounds__(256, 3) void gemm_gate_up(
    const u16* __restrict__ Xi, const u16* __restrict__ WgT,
    const u16* __restrict__ WuT, const int* __restrict__ cnt,
    u16* __restrict__ H) {
  __shared__ u16 As[TILE_U16];   // 16 KiB
  __shared__ u16 Bg[TILE_U16];   // 16 KiB
  __shared__ u16 Bu[TILE_U16];   // 16 KiB

  const int lin = xcd_lin(blockIdx.x, GU_BLKS);
  const int t = lin / NT_GU;
  const int n0t = lin - t * NT_GU;   // 0..10, fastest
  int e, row0, valid;
  if (!tile_map(cnt, t, e, row0, valid)) return;

  const int tid = threadIdx.x;
  const int lane = tid & 63;
  const int wave = tid >> 6;                 // 0..3
  const int wr = (wave >> 1) * 64, wcn = (wave & 1) * 64;
  const int l15 = lane & 15, l4 = lane >> 4;
  const int swz = l15 & 7;

  const u16* pA[4];
#pragma unroll
  for (int q = 0; q < 4; ++q) {
    int u = q * 256 + tid;
    int lr = u >> 3, cs = u & 7;
    int R = row0 + (lr < valid ? lr : 0);
    int srcc = cs ^ (lr & 7) ^ (R & 7);
    pA[q] = Xi + (size_t)(R >> 7) * XI_RS + (size_t)(R & 127) * 64 + srcc * 8;
  }
  const size_t btb = (((size_t)e * NT_GU + n0t) * 32) * TILE_U16;
  const u16* pBg[4];
  const u16* pBu[4];
#pragma unroll
  for (int q = 0; q < 4; ++q) {
    pBg[q] = WgT + btb + (q * 256 + tid) * 8;
    pBu[q] = WuT + btb + (q * 256 + tid) * 8;
  }

  const int arow = (wr + l15) * 64;
  const int brow = (wcn + l15) * 64;
  const int c0 = (l4 ^ swz) * 8;
  const int c1 = ((4 + l4) ^ swz) * 8;
  const u16* pa0 = &As[arow + c0];
  const u16* pa1 = &As[arow + c1];
  const u16* pg0 = &Bg[brow + c0];
  const u16* pg1 = &Bg[brow + c1];
  const u16* pu0 = &Bu[brow + c0];
  const u16* pu1 = &Bu[brow + c1];

  f32x4 accg[4][4], accu[4][4];
#pragma unroll
  for (int i = 0; i < 4; i++)
#pragma unroll
    for (int j = 0; j < 4; j++) {
      accg[i][j] = (f32x4){0.f, 0.f, 0.f, 0.f};
      accu[i][j] = (f32x4){0.f, 0.f, 0.f, 0.f};
    }

  for (int kt = 0; kt < 32; ++kt) {
    const size_t ko = (size_t)kt * TILE_U16;
#pragma unroll
    for (int q = 0; q < 4; ++q) {
      const int u8 = (q * 256 + tid) * 8;
      gll16(pA[q] + ko, &As[u8]);
      gll16(pBg[q] + ko, &Bg[u8]);
      gll16(pBu[q] + ko, &Bu[u8]);
    }
    __syncthreads();
#pragma unroll
    for (int kh = 0; kh < 2; ++kh) {
      bf16x8 af[4], bgv[4], buv[4];
#pragma unroll
      for (int i = 0; i < 4; ++i)
        af[i] = ld_frag((kh ? pa1 : pa0) + i * 1024);
#pragma unroll
      for (int j = 0; j < 4; ++j) {
        bgv[j] = ld_frag((kh ? pg1 : pg0) + j * 1024);
        buv[j] = ld_frag((kh ? pu1 : pu0) + j * 1024);
      }
#pragma unroll
      for (int j = 0; j < 4; ++j)
#pragma unroll
        for (int i = 0; i < 4; ++i) {
          accg[i][j] = MFMA(af[i], bgv[j], accg[i][j]);
          accu[i][j] = MFMA(af[i], buv[j], accu[i][j]);
        }
    }
    __syncthreads();
  }

#pragma unroll
  for (int j = 0; j < 4; ++j) {
    int col = n0t * 128 + wcn + j * 16 + l15;
    int kt_h = col >> 6, cc = (col & 63) >> 3, ce = col & 7;
#pragma unroll
    for (int i = 0; i < 4; ++i) {
      f32x4 g = accg[i][j], u = accu[i][j];
#pragma unroll
      for (int r = 0; r < 4; ++r) {
        int rl = wr + i * 16 + l4 * 4 + r;
        if (rl < valid) {
          int R = row0 + rl;
          float gv = g[r];
          float hv = gv / (1.f + __expf(-gv)) * u[r];
          size_t idx = (size_t)(R >> 7) * HT_RS + (size_t)kt_h * TILE_U16 +
                       (size_t)(R & 127) * 64 + ((cc ^ (R & 7)) * 8) + ce;
          H[idx] = f2bf(hv);
        }
      }
    }
  }
}

// ---------------------------------------------------------------------------
// Down grouped GEMM. 128x256 tile, 256 thr, 4 waves each 64x128 (4x8 frags).
// LDS 48 KiB, 3 blocks/CU. Grid: linear 2176; n0t fastest within XCD chunk.
// ---------------------------------------------------------------------------
__global__ __launch_bounds__(256, 3) void gemm_down(
    const u16* __restrict__ Ht, const u16* __restrict__ WdT,
    const int* __restrict__ cnt, float* __restrict__ Out) {
  __shared__ u16 As[TILE_U16];       // 16 KiB (128 rows x 64)
  __shared__ u16 Bs[2 * TILE_U16];   // 32 KiB (256 cols as 2 images)

  const int lin = xcd_lin(blockIdx.x, DN_BLKS);
  const int t = lin >> 3;
  const int n0t = lin & 7;           // 0..7, fastest
  int e, row0, valid;
  if (!tile_map(cnt, t, e, row0, valid)) return;

  const int tid = threadIdx.x;
  const int lane = tid & 63;
  const int wave = tid >> 6;                  // 0..3
  const int wr = (wave >> 1) * 64;            // 0,64
  const int wcn = (wave & 1) * 128;           // 0,128
  const int l15 = lane & 15, l4 = lane >> 4;
  const int swz = l15 & 7;

  const u16* pA[4];
#pragma unroll
  for (int q = 0; q < 4; ++q) {
    int u = q * 256 + tid;
    int lr = u >> 3, cs = u & 7;
    int R = row0 + (lr < valid ? lr : 0);
    int srcc = cs ^ (lr & 7) ^ (R & 7);
    pA[q] = Ht + (size_t)(R >> 7) * HT_RS + (size_t)(R & 127) * 64 + srcc * 8;
  }
  const size_t btb0 = (((size_t)e * 16 + n0t * 2) * 22) * TILE_U16;
  const size_t btb1 = (((size_t)e * 16 + n0t * 2 + 1) * 22) * TILE_U16;
  const u16* pB[8];
#pragma unroll
  for (int q = 0; q < 4; ++q) {
    pB[q] = WdT + btb0 + (q * 256 + tid) * 8;
    pB[q + 4] = WdT + btb1 + (q * 256 + tid) * 8;
  }

  const int arow = (wr + l15) * 64;
  const int c0 = (l4 ^ swz) * 8;
  const int c1 = ((4 + l4) ^ swz) * 8;
  const u16* pa0 = &As[arow + c0];
  const u16* pa1 = &As[arow + c1];
  const u16* pb0 = &Bs[(wcn >> 7) * TILE_U16 + l15 * 64 + c0];
  const u16* pb1 = &Bs[(wcn >> 7) * TILE_U16 + l15 * 64 + c1];

  f32x4 acc[4][8];
#pragma unroll
  for (int i = 0; i < 4; i++)
#pragma unroll
    for (int j = 0; j < 8; j++) acc[i][j] = (f32x4){0.f, 0.f, 0.f, 0.f};

  for (int kt = 0; kt < 22; ++kt) {
    const size_t ko = (size_t)kt * TILE_U16;
#pragma unroll
    for (int q = 0; q < 4; ++q) gll16(pA[q] + ko, &As[(q * 256 + tid) * 8]);
#pragma unroll
    for (int q = 0; q < 8; ++q) gll16(pB[q] + ko, &Bs[(q * 256 + tid) * 8]);
    __syncthreads();
#pragma unroll
    for (int kh = 0; kh < 2; ++kh) {
      bf16x8 af[4];
#pragma unroll
      for (int i = 0; i < 4; ++i)
        af[i] = ld_frag((kh ? pa1 : pa0) + i * 1024);
#pragma unroll
      for (int j = 0; j < 8; ++j) {
        bf16x8 bv = ld_frag((kh ? pb1 : pb0) + j * 1024);
#pragma unroll
        for (int i = 0; i < 4; ++i) acc[i][j] = MFMA(af[i], bv, acc[i][j]);
      }
    }
    __syncthreads();
  }

#pragma unroll
  for (int j = 0; j < 8; ++j) {
    const int colb = n0t * 256 + wcn + j * 16 + l15;
#pragma unroll
    for (int i = 0; i < 4; ++i) {
#pragma unroll
      for (int r = 0; r < 4; ++r) {
        int rl = wr + i * 16 + l4 * 4 + r;
        if (rl < valid)
          Out[(size_t)(row0 + rl) * DM + colb] = acc[i][j][r];
      }
    }
  }
}

extern "C" void kernel_launch(void* const* d_in, const int* in_sizes, int n_in,
                              void* d_out, int out_size, void* d_ws, size_t ws_size,
                              hipStream_t stream) {
  const float* inp = (const float*)d_in[0];
  const float* w_gate = (const float*)d_in[1];
  const float* w_up = (const float*)d_in[2];
  const float* w_down = (const float*)d_in[3];
  const int* cnt = (const int*)d_in[4];
  float* out = (float*)d_out;

  const size_t XI_ELEMS = (size_t)NTOK * DM;       // 128 MiB as bf16
  const size_t WELEMS = (size_t)E_NUM * DM * DH;   // 88 MiB as bf16
  if (ws_size < (XI_ELEMS + 3 * WELEMS) * sizeof(u16)) return;

  u16* Xi = (u16*)d_ws;        // X images [256][32][8192]
  u16* wgT = Xi + XI_ELEMS;    // gate tiles [E][11][32][8192]; later w_down
  u16* wuT = wgT + WELEMS;     // up tiles
  u16* Ht = wuT + WELEMS;      // H images [256][22][8192]

  xtile<<<dim3(32, 256), 256, 0, stream>>>(inp, Xi);
  wtile<<<dim3(DM / 64, DH / 128, E_NUM), 256, 0, stream>>>(w_gate, wgT, DM, DH);
  wtile<<<dim3(DM / 64, DH / 128, E_NUM), 256, 0, stream>>>(w_up, wuT, DM, DH);
  gemm_gate_up<<<dim3(GU_BLKS), 256, 0, stream>>>(Xi, wgT, wuT, cnt, Ht);
  // wgT region dead now; reuse for w_down tiles [E][16][22][8192]
  wtile<<<dim3(DH / 64, DM / 128, E_NUM), 256, 0, stream>>>(w_down, wgT, DH, DM);
  gemm_down<<<dim3(DN_BLKS), 256, 0, stream>>>(Ht, wgT, cnt, out);
}